// Round 8
// baseline (105.538 us; speedup 1.0000x reference)
//
#include <hip/hip_runtime.h>
#include <math.h>

typedef _Float16 v8h __attribute__((ext_vector_type(8)));
typedef _Float16 v4h __attribute__((ext_vector_type(4)));
typedef float v4f __attribute__((ext_vector_type(4)));

#define MFMA16(a, b, c) __builtin_amdgcn_mfma_f32_16x16x32_f16((a), (b), (c), 0, 0, 0)

// swizzled tile addressing (byte offsets)
// rows of 64 fp16 (128 B):  XOR 16B-slot with row&7
#define TA64(row, colb)  ((((row) * 128) + (colb)) ^ (((row) & 7) << 4))
// rows of 128 fp16 (256 B): XOR 16B-slot with row&15
#define TA128(row, colb) ((((row) * 256) + (colb)) ^ (((row) & 15) << 4))

__device__ __forceinline__ unsigned int pk_f16(float a, float b) {
    return __builtin_bit_cast(unsigned int, __builtin_amdgcn_cvt_pkrtz(a, b));
}

// ---------------------------------------------------------------- k_prep ----
// Wt[c][d] = fp16(W_w[d][c]); sc/bi fold conv-bias + BN.
__global__ __launch_bounds__(256) void k_prep(
    const float* __restrict__ Ww, const float* __restrict__ Wb,
    const float* __restrict__ gamma, const float* __restrict__ beta,
    const float* __restrict__ mean, const float* __restrict__ var,
    _Float16* __restrict__ Wt, float* __restrict__ sc, float* __restrict__ bi)
{
    int t = threadIdx.x;
    #pragma unroll
    for (int rep = 0; rep < 32; ++rep) {
        int idx = rep * 256 + t;          // 64*128 = 8192 elements
        int d = idx >> 7, c = idx & 127;  // W_w is [64][128], coalesced read
        Wt[c * 64 + d] = (_Float16)Ww[idx];
    }
    if (t < 128) {
        float inv = gamma[t] * rsqrtf(var[t] + 1e-4f);
        sc[t] = inv;
        bi[t] = (Wb[t] - mean[t]) * inv + beta[t];
    }
}

// ---------------------------------------------------------------- k_proj ----
// fp32 projections (precision-critical), outputs fp16:
// theta/phi token-major [32768][64]; g transposed gT[b][64][4096].
__global__ __launch_bounds__(256) void k_proj(
    const float* __restrict__ x,
    const float* __restrict__ tw, const float* __restrict__ tb,
    const float* __restrict__ pw, const float* __restrict__ pb,
    const float* __restrict__ gw, const float* __restrict__ gb,
    _Float16* __restrict__ theta, _Float16* __restrict__ phi,
    _Float16* __restrict__ gT)
{
    __shared__ __align__(16) float xl[64][132];   // +4 pad
    __shared__ __align__(16) float wl[64][68];
    const int t = threadIdx.x;
    const int tok0 = blockIdx.x * 64;

    #pragma unroll
    for (int rep = 0; rep < 8; ++rep) {           // stage x tile [64][128]
        int chunk = rep * 256 + t;
        int tk = chunk >> 5, k = (chunk & 31) * 4;
        *(float4*)&xl[tk][k] = *(const float4*)(x + (size_t)(tok0 + tk) * 128 + k);
    }
    const int tg = t >> 4, og = t & 15;

    for (int p = 0; p < 3; ++p) {
        const float* wmat = (p == 0) ? tw : (p == 1) ? pw : gw;
        const float* bias = (p == 0) ? tb : (p == 1) ? pb : gb;
        float acc[4][4] = {};
        #pragma unroll
        for (int kh = 0; kh < 2; ++kh) {
            __syncthreads();                      // prev compute done
            #pragma unroll
            for (int rep = 0; rep < 4; ++rep) {   // stage W half [64][64]
                int chunk = rep * 256 + t;
                int kk = chunk >> 4, o = (chunk & 15) * 4;
                *(float4*)&wl[kk][o] = *(const float4*)(wmat + (kh * 64 + kk) * 64 + o);
            }
            __syncthreads();
            #pragma unroll 4
            for (int k = 0; k < 64; ++k) {
                float4 wv = *(const float4*)&wl[k][og * 4];
                #pragma unroll
                for (int i = 0; i < 4; ++i) {
                    float xv = xl[tg * 4 + i][kh * 64 + k];
                    acc[i][0] = fmaf(xv, wv.x, acc[i][0]);
                    acc[i][1] = fmaf(xv, wv.y, acc[i][1]);
                    acc[i][2] = fmaf(xv, wv.z, acc[i][2]);
                    acc[i][3] = fmaf(xv, wv.w, acc[i][3]);
                }
            }
        }
        float4 bv = *(const float4*)(bias + og * 4);
        const float bvv[4] = {bv.x, bv.y, bv.z, bv.w};
        if (p < 2) {
            _Float16* dst = (p == 0) ? theta : phi;
            #pragma unroll
            for (int i = 0; i < 4; ++i) {
                int tok = tok0 + tg * 4 + i;
                v4h o4;
                #pragma unroll
                for (int j = 0; j < 4; ++j)
                    o4[j] = (_Float16)(acc[i][j] + bvv[j]);
                *(v4h*)(dst + (size_t)tok * 64 + og * 4) = o4;
            }
        } else {
            #pragma unroll
            for (int i = 0; i < 4; ++i) {
                int tok = tok0 + tg * 4 + i;
                int bb = tok >> 12, n = tok & 4095;
                #pragma unroll
                for (int j = 0; j < 4; ++j)
                    gT[((size_t)bb * 64 + og * 4 + j) * 4096 + n] =
                        (_Float16)(acc[i][j] + bvv[j]);
            }
        }
    }
}

// ---------------------------------------------------------------- k_attn ----
// Flash attention + fused epilogue, all-fp16 MFMA.
// Grid (64,8) = 512 blocks (2/CU for 4 waves/SIMD), 512 threads = 8 waves.
// Block owns 64 queries; wave = (q-tile qt = w&3 [16 q], key-half kh = w>>2).
// Each wave runs flash over its 64-key half of each 128-key tile with private
// (m,l,yacc); kh pairs merged at the end via LDS flash-combine with PER-QUERY
// factors (a0/a1 shfl'd from lane 20*hi+rr — the r7 bug was using query-lo's).
// SWAPPED QK^T: S = MFMA(A=phi, B=theta) -> lane owns query lo's P-slice.
// LDS 48KB -> 2 blocks/CU. W^T read directly from global in epilogue (L2-hot).
__global__ __launch_bounds__(512, 4) void k_attn(
    const _Float16* __restrict__ theta,
    const _Float16* __restrict__ phi,
    const _Float16* __restrict__ gT,
    const _Float16* __restrict__ Wt,
    const float* __restrict__ sc, const float* __restrict__ bi,
    const float* __restrict__ x, float* __restrict__ out)
{
    __shared__ __align__(16) _Float16 ph_l[128 * 64];    // keys x dims   (16K)
    __shared__ __align__(16) _Float16 gv_l[64 * 128];    // dims x keys   (16K)
    __shared__ __align__(16) _Float16 scr[8][16 * 64];   // per-wave P/y  (16K)

    const int t = threadIdx.x;
    const int w = t >> 6, l = t & 63, hi = l >> 4, lo = l & 15;
    const int qt = w & 3, kh = w >> 2;
    const int b = blockIdx.y, qb = blockIdx.x;
    const int q0 = qb * 64 + qt * 16;
    const size_t tok0 = (size_t)b * 4096 + q0;

    char* phL = (char*)ph_l;
    char* gvL = (char*)gv_l;
    char* scrc = (char*)&scr[w][0];

    v8h thA[2];                          // hoisted Q fragments
    #pragma unroll
    for (int kc = 0; kc < 2; ++kc)
        thA[kc] = *(const v8h*)(theta + (tok0 + lo) * 64 + kc * 32 + hi * 8);

    const _Float16* phb = phi + (size_t)b * 4096 * 64;
    const _Float16* gvb = gT + (size_t)b * 64 * 4096;

    v4f yacc[4];                         // y[q'=4hi+rr][d=16dt+lo]
    #pragma unroll
    for (int dt = 0; dt < 4; ++dt) yacc[dt] = (v4f){0.f, 0.f, 0.f, 0.f};
    float mrow = -INFINITY, lrow = 0.f;  // per-lane: query q = lo

    // staging map: ph 128x64 (8 chunks/row), gv 64x128 (16 chunks/row)
    const int phr = t >> 3, phcB = (t & 7) * 16;   // + row 64 second chunk
    const int gvr = t >> 4, gvcB = (t & 15) * 16;  // + row 32 second chunk
    const int phA0 = TA64(phr, phcB), phA1 = TA64(phr + 64, phcB);
    const int gvA0 = TA128(gvr, gvcB), gvA1 = TA128(gvr + 32, gvcB);
    const _Float16* pPh = phb + (size_t)phr * 64 + (phcB >> 1);
    const _Float16* pGv = gvb + (size_t)gvr * 4096 + (gvcB >> 1);

    // prefetch tile 0
    v8h pf0 = *(const v8h*)(pPh);
    v8h pf1 = *(const v8h*)(pPh + 64 * 64);
    v8h pf2 = *(const v8h*)(pGv);
    v8h pf3 = *(const v8h*)(pGv + (size_t)32 * 4096);
    pPh += 128 * 64; pGv += 128;

    for (int kt = 0; kt < 32; ++kt) {
        __syncthreads();                 // prev tile consumed
        *(v8h*)(phL + phA0) = pf0;
        *(v8h*)(phL + phA1) = pf1;
        *(v8h*)(gvL + gvA0) = pf2;
        *(v8h*)(gvL + gvA1) = pf3;
        __syncthreads();
        if (kt < 31) {                   // prefetch next tile under compute
            pf0 = *(const v8h*)(pPh);
            pf1 = *(const v8h*)(pPh + 64 * 64);
            pf2 = *(const v8h*)(pGv);
            pf3 = *(const v8h*)(pGv + (size_t)32 * 4096);
            pPh += 128 * 64; pGv += 128;
        }
        // ---- QK^T swapped over this wave's 64-key half:
        //      lane -> S[key_local=16s+4hi+rr][q=lo]
        v4f S[4];
        __builtin_amdgcn_s_setprio(1);
        #pragma unroll
        for (int s = 0; s < 4; ++s) {
            int row = kh * 64 + s * 16 + lo;
            v8h a0 = *(const v8h*)(phL + TA64(row, hi * 16));
            v8h a1 = *(const v8h*)(phL + TA64(row, 64 + hi * 16));
            v4f acc = MFMA16(a0, thA[0], ((v4f){0.f, 0.f, 0.f, 0.f}));
            S[s] = MFMA16(a1, thA[1], acc);
        }
        __builtin_amdgcn_s_setprio(0);
        // ---- online softmax (in-lane tree + xor16/xor32)
        float vmax = -INFINITY;
        #pragma unroll
        for (int s = 0; s < 4; ++s)
            vmax = fmaxf(vmax, fmaxf(fmaxf(S[s][0], S[s][1]),
                                     fmaxf(S[s][2], S[s][3])));
        vmax = fmaxf(vmax, __shfl_xor(vmax, 16));
        vmax = fmaxf(vmax, __shfl_xor(vmax, 32));
        float a = 1.0f;
        if (!__all(vmax <= mrow + 8.0f)) {   // defer-max (THR=8)
            float mn = fmaxf(mrow, vmax);
            a = __expf(mrow - mn);           // 0 on first tile
            mrow = mn;
            float aq[4];
            #pragma unroll
            for (int rr = 0; rr < 4; ++rr)
                aq[rr] = __shfl(a, 20 * hi + rr);  // a of query 4hi+rr
            #pragma unroll
            for (int dt = 0; dt < 4; ++dt)
                #pragma unroll
                for (int rr = 0; rr < 4; ++rr)
                    yacc[dt][rr] *= aq[rr];
        }
        float psum = 0.f;
        #pragma unroll
        for (int s = 0; s < 4; ++s) {
            #pragma unroll
            for (int rr = 0; rr < 4; ++rr)
                S[s][rr] = __expf(S[s][rr] - mrow);
            psum += (S[s][0] + S[s][1]) + (S[s][2] + S[s][3]);
        }
        psum += __shfl_xor(psum, 16);
        psum += __shfl_xor(psum, 32);
        lrow = lrow * a + psum;
        // ---- P -> scr (fp16, packed b64): row = query lo, key 16s+4hi+rr
        #pragma unroll
        for (int s = 0; s < 4; ++s) {
            uint2 pk;
            pk.x = pk_f16(S[s][0], S[s][1]);
            pk.y = pk_f16(S[s][2], S[s][3]);
            *(uint2*)(scrc + TA64(lo, s * 32 + hi * 8)) = pk;
        }
        // ---- PV: y += P(16q x 64k) . g(64k x 64d), keys kh*64 + ...
        v8h pA[2];
        #pragma unroll
        for (int kc = 0; kc < 2; ++kc)
            pA[kc] = *(const v8h*)(scrc + TA64(lo, kc * 64 + hi * 16));
        __builtin_amdgcn_s_setprio(1);
        #pragma unroll
        for (int kc = 0; kc < 2; ++kc)
            #pragma unroll
            for (int dt = 0; dt < 4; ++dt) {
                v8h gB = *(const v8h*)(gvL +
                    TA128(dt * 16 + lo, kh * 128 + kc * 64 + hi * 16));
                yacc[dt] = MFMA16(pA[kc], gB, yacc[dt]);
            }
        __builtin_amdgcn_s_setprio(0);
    }

    // ---- flash-combine of kh pairs (reuse ph_l/gv_l as fp32 scratch)
    __syncthreads();
    float* cy  = (float*)ph_l;           // [4 qt][64 lanes][16]  = 16K
    float* cml = (float*)gv_l;           // [4 qt][64 lanes][2]   = 2K
    if (kh == 1) {
        int byacc = (qt * 64 + l) * 16;
        #pragma unroll
        for (int dt = 0; dt < 4; ++dt)
            #pragma unroll
            for (int rr = 0; rr < 4; ++rr)
                cy[byacc + dt * 4 + rr] = yacc[dt][rr];
        cml[(qt * 64 + l) * 2 + 0] = mrow;
        cml[(qt * 64 + l) * 2 + 1] = lrow;
    }
    __syncthreads();
    if (kh != 0) return;
    {
        int byacc = (qt * 64 + l) * 16;
        float m1 = cml[(qt * 64 + l) * 2 + 0];
        float l1 = cml[(qt * 64 + l) * 2 + 1];
        float mm = fmaxf(mrow, m1);
        float a0 = __expf(mrow - mm), a1 = __expf(m1 - mm);  // query lo's
        lrow = lrow * a0 + l1 * a1;
        // yacc[dt][rr] belongs to query 4hi+rr -> fetch ITS factors
        float a0q[4], a1q[4];
        #pragma unroll
        for (int rr = 0; rr < 4; ++rr) {
            a0q[rr] = __shfl(a0, 20 * hi + rr);
            a1q[rr] = __shfl(a1, 20 * hi + rr);
        }
        #pragma unroll
        for (int dt = 0; dt < 4; ++dt)
            #pragma unroll
            for (int rr = 0; rr < 4; ++rr)
                yacc[dt][rr] = yacc[dt][rr] * a0q[rr]
                             + cy[byacc + dt * 4 + rr] * a1q[rr];
    }

    // ---- epilogue: y/l -> fp16 scr -> wy = y @ W^T -> BN + residual
    float lq[4];
    #pragma unroll
    for (int rr = 0; rr < 4; ++rr)
        lq[rr] = __shfl(lrow, 20 * hi + rr);     // lrow of query 4hi+rr
    #pragma unroll
    for (int rr = 0; rr < 4; ++rr) {
        float inv = 1.0f / lq[rr];
        int m = hi * 4 + rr;                     // query row
        #pragma unroll
        for (int dt = 0; dt < 4; ++dt)
            *(_Float16*)(scrc + TA64(m, (dt * 16 + lo) * 2)) =
                (_Float16)(yacc[dt][rr] * inv);
    }
    v8h yA[2];
    #pragma unroll
    for (int kc = 0; kc < 2; ++kc)
        yA[kc] = *(const v8h*)(scrc + TA64(lo, kc * 64 + hi * 16));

    const float* xb = x + tok0 * 128;
    float* ob = out + tok0 * 128;
    #pragma unroll
    for (int ct = 0; ct < 8; ++ct) {
        int c = ct * 16 + lo;
        v8h wB0 = *(const v8h*)(Wt + c * 64 + hi * 8);        // L2-hot direct
        v8h wB1 = *(const v8h*)(Wt + c * 64 + 32 + hi * 8);
        float scc = sc[c], bic = bi[c];
        v4f wy = MFMA16(yA[0], wB0, ((v4f){0.f, 0.f, 0.f, 0.f}));
        wy = MFMA16(yA[1], wB1, wy);
        #pragma unroll
        for (int rr = 0; rr < 4; ++rr) {
            int m = hi * 4 + rr;
            ob[(size_t)m * 128 + c] = wy[rr] * scc + bic + xb[(size_t)m * 128 + c];
        }
    }
}

// ------------------------------------------------------------------ launch --
extern "C" void kernel_launch(void* const* d_in, const int* in_sizes, int n_in,
                              void* d_out, int out_size, void* d_ws, size_t ws_size,
                              hipStream_t stream) {
    const float* x     = (const float*)d_in[0];
    const float* tw    = (const float*)d_in[1];
    const float* tb    = (const float*)d_in[2];
    const float* pw    = (const float*)d_in[3];
    const float* pb    = (const float*)d_in[4];
    const float* gw    = (const float*)d_in[5];
    const float* gb    = (const float*)d_in[6];
    const float* Ww    = (const float*)d_in[7];
    const float* Wb    = (const float*)d_in[8];
    const float* gamma = (const float*)d_in[9];
    const float* beta  = (const float*)d_in[10];
    const float* mean  = (const float*)d_in[11];
    const float* var   = (const float*)d_in[12];

    char* ws = (char*)d_ws;
    _Float16* theta = (_Float16*)ws;                   // 4 MB
    _Float16* phi   = (_Float16*)(ws + (4u << 20));    // 4 MB
    _Float16* gT    = (_Float16*)(ws + (8u << 20));    // 4 MB
    _Float16* Wt    = (_Float16*)(ws + (12u << 20));   // 16 KB
    float* sc       = (float*)(ws + (12u << 20) + (1u << 16));
    float* bi       = sc + 128;

    k_prep<<<1, 256, 0, stream>>>(Ww, Wb, gamma, beta, mean, var, Wt, sc, bi);
    k_proj<<<512, 256, 0, stream>>>(x, tw, tb, pw, pb, gw, gb, theta, phi, gT);
    k_attn<<<dim3(64, 8), 512, 0, stream>>>(theta, phi, gT, Wt, sc, bi,
                                            x, (float*)d_out);
}